// Round 1
// baseline (346.848 us; speedup 1.0000x reference)
//
#include <hip/hip_runtime.h>
#include <cstdint>
#include <cstddef>

#define NQ 4
#define DIM 64
#define FAN 68
#define T_TOTAL 128
#define BATCH 4096

__device__ __forceinline__ float sigmoid_(float x) {
    return 1.0f / (1.0f + __expf(-x));
}
__device__ __forceinline__ float tanh_(float x) {
    // tanh(x) = 1 - 2/(exp(2x)+1); correct limits at +-inf
    return 1.0f - 2.0f / (__expf(2.0f * x) + 1.0f);
}

// K1: pre[row,16] = x[row,0:64] @ W[:, 0:64]^T + b + theta   (row = t*B + b within chunk)
__global__ __launch_bounds__(256) void qlstm_pre(
    const float* __restrict__ x,   // [nrows, 64]
    const float* __restrict__ Wf, const float* __restrict__ bf,
    const float* __restrict__ Wi, const float* __restrict__ bi,
    const float* __restrict__ Wu, const float* __restrict__ bu,
    const float* __restrict__ Wo, const float* __restrict__ bo,
    const float* __restrict__ thetas,   // [4,4]
    float* __restrict__ pre,            // [nrows, 16]
    int nrows)
{
    int row = blockIdx.x * 256 + threadIdx.x;
    if (row >= nrows) return;

    const float4* xv = reinterpret_cast<const float4*>(x + (size_t)row * DIM);
    float4 xr[16];
#pragma unroll
    for (int j = 0; j < 16; ++j) xr[j] = xv[j];

    const float* Ws[4] = {Wf, Wi, Wu, Wo};
    const float* bs[4] = {bf, bi, bu, bo};

    float acc[16];
#pragma unroll
    for (int G = 0; G < 4; ++G) {
#pragma unroll
        for (int q = 0; q < NQ; ++q) {
            float a = bs[G][q] + thetas[G * NQ + q];
            const float4* wr = reinterpret_cast<const float4*>(Ws[G] + q * FAN); // 68*4 bytes: 16B aligned
#pragma unroll
            for (int j = 0; j < 16; ++j) {
                float4 w = wr[j];
                a = fmaf(xr[j].x, w.x, a);
                a = fmaf(xr[j].y, w.y, a);
                a = fmaf(xr[j].z, w.z, a);
                a = fmaf(xr[j].w, w.w, a);
            }
            acc[G * 4 + q] = a;
        }
    }

    float4* pv = reinterpret_cast<float4*>(pre + (size_t)row * 16);
#pragma unroll
    for (int k = 0; k < 4; ++k)
        pv[k] = make_float4(acc[4 * k], acc[4 * k + 1], acc[4 * k + 2], acc[4 * k + 3]);
}

// K2: sequential LSTM recurrence over this chunk's timesteps. One thread per batch element.
__global__ __launch_bounds__(64) void qlstm_rec(
    const float* __restrict__ pre,   // [chunkT, B, 16]
    const float* __restrict__ Wf, const float* __restrict__ Wi,
    const float* __restrict__ Wu, const float* __restrict__ Wo,
    float* __restrict__ out,         // full output buffer
    float* __restrict__ state,       // [2, B, 4]  (h then c)
    int t0, int chunkT, int isFirst, int isLast)
{
    int b = blockIdx.x * 64 + threadIdx.x;   // grid covers BATCH exactly

    const float* Ws[4] = {Wf, Wi, Wu, Wo};
    float wh[4][4][4];
#pragma unroll
    for (int G = 0; G < 4; ++G)
#pragma unroll
        for (int q = 0; q < 4; ++q)
#pragma unroll
            for (int j = 0; j < 4; ++j)
                wh[G][q][j] = Ws[G][q * FAN + DIM + j];

    float h[4], c[4];
    if (isFirst) {
#pragma unroll
        for (int q = 0; q < 4; ++q) { h[q] = 0.0f; c[q] = 0.0f; }
    } else {
        float4 hv = *reinterpret_cast<const float4*>(state + (size_t)b * 4);
        float4 cv = *reinterpret_cast<const float4*>(state + (size_t)BATCH * 4 + (size_t)b * 4);
        h[0] = hv.x; h[1] = hv.y; h[2] = hv.z; h[3] = hv.w;
        c[0] = cv.x; c[1] = cv.y; c[2] = cv.z; c[3] = cv.w;
    }

    // prefetch first pre row
    float4 p[4];
    {
        const float4* pv = reinterpret_cast<const float4*>(pre + ((size_t)0 * BATCH + b) * 16);
#pragma unroll
        for (int k = 0; k < 4; ++k) p[k] = pv[k];
    }

    for (int tt = 0; tt < chunkT; ++tt) {
        // prefetch next (clamped address so no divergence, value unused on last iter)
        int tn = (tt + 1 < chunkT) ? (tt + 1) : tt;
        const float4* pvn = reinterpret_cast<const float4*>(pre + ((size_t)tn * BATCH + b) * 16);
        float4 pn[4];
#pragma unroll
        for (int k = 0; k < 4; ++k) pn[k] = pvn[k];

        float pa[16];
        pa[0] = p[0].x; pa[1] = p[0].y; pa[2]  = p[0].z; pa[3]  = p[0].w;
        pa[4] = p[1].x; pa[5] = p[1].y; pa[6]  = p[1].z; pa[7]  = p[1].w;
        pa[8] = p[2].x; pa[9] = p[2].y; pa[10] = p[2].z; pa[11] = p[2].w;
        pa[12] = p[3].x; pa[13] = p[3].y; pa[14] = p[3].z; pa[15] = p[3].w;

        float z[4][4];
#pragma unroll
        for (int G = 0; G < 4; ++G) {
            float cg[4];
#pragma unroll
            for (int q = 0; q < 4; ++q) {
                float a = pa[G * 4 + q];
#pragma unroll
                for (int j = 0; j < 4; ++j) a = fmaf(wh[G][q][j], h[j], a);
                cg[q] = __cosf(a);
            }
            z[G][0] = cg[1] * (cg[2] * cg[3]);
            z[G][1] = cg[0] * cg[1];
            z[G][2] = z[G][1] * cg[2];
            z[G][3] = z[G][2] * cg[3];
        }

#pragma unroll
        for (int q = 0; q < 4; ++q) {
            float fq = sigmoid_(z[0][q]);
            float iq = sigmoid_(z[1][q]);
            float uq = tanh_(z[2][q]);
            float oq = sigmoid_(z[3][q]);
            float cn = fmaf(fq, c[q], iq * uq);
            c[q] = cn;
            h[q] = oq * tanh_(cn);
        }

        *reinterpret_cast<float4*>(out + ((size_t)(t0 + tt) * BATCH + b) * 4) =
            make_float4(h[0], h[1], h[2], h[3]);

#pragma unroll
        for (int k = 0; k < 4; ++k) p[k] = pn[k];
    }

    // persist state for next chunk
    *reinterpret_cast<float4*>(state + (size_t)b * 4) = make_float4(h[0], h[1], h[2], h[3]);
    *reinterpret_cast<float4*>(state + (size_t)BATCH * 4 + (size_t)b * 4) =
        make_float4(c[0], c[1], c[2], c[3]);

    if (isLast) {
        size_t tail = (size_t)T_TOTAL * BATCH * 4;
        *reinterpret_cast<float4*>(out + tail + (size_t)b * 4) =
            make_float4(h[0], h[1], h[2], h[3]);
        *reinterpret_cast<float4*>(out + tail + (size_t)BATCH * 4 + (size_t)b * 4) =
            make_float4(c[0], c[1], c[2], c[3]);
    }
}

extern "C" void kernel_launch(void* const* d_in, const int* in_sizes, int n_in,
                              void* d_out, int out_size, void* d_ws, size_t ws_size,
                              hipStream_t stream)
{
    const float* x  = (const float*)d_in[0];
    const float* Wf = (const float*)d_in[1];
    const float* bf = (const float*)d_in[2];
    const float* Wi = (const float*)d_in[3];
    const float* bi = (const float*)d_in[4];
    const float* Wu = (const float*)d_in[5];
    const float* bu = (const float*)d_in[6];
    const float* Wo = (const float*)d_in[7];
    const float* bo = (const float*)d_in[8];
    const float* th = (const float*)d_in[9];
    float* out = (float*)d_out;

    const size_t stateBytes = 2 * (size_t)BATCH * 4 * sizeof(float);  // 128 KB
    const size_t perT       = (size_t)BATCH * 16 * sizeof(float);     // 256 KB per timestep
    size_t avail = (ws_size > stateBytes) ? (ws_size - stateBytes) : 0;
    int chunkT = (int)(avail / perT);
    if (chunkT > T_TOTAL) chunkT = T_TOTAL;
    if (chunkT < 1) chunkT = 1;   // requires ws_size >= ~384KB

    float* pre = (float*)d_ws;
    size_t stateOff = (ws_size - stateBytes) & ~(size_t)15;
    float* state = (float*)((char*)d_ws + stateOff);

    for (int t0 = 0; t0 < T_TOTAL; t0 += chunkT) {
        int ct = (T_TOTAL - t0 < chunkT) ? (T_TOTAL - t0) : chunkT;
        int nrows = ct * BATCH;
        qlstm_pre<<<(nrows + 255) / 256, 256, 0, stream>>>(
            x + (size_t)t0 * BATCH * DIM,
            Wf, bf, Wi, bi, Wu, bu, Wo, bo, th, pre, nrows);
        qlstm_rec<<<BATCH / 64, 64, 0, stream>>>(
            pre, Wf, Wi, Wu, Wo, out, state,
            t0, ct, (t0 == 0) ? 1 : 0, (t0 + ct >= T_TOTAL) ? 1 : 0);
    }
}

// Round 7
// 260.350 us; speedup vs baseline: 1.3322x; 1.3322x over previous
//
#include <hip/hip_runtime.h>
#include <cstdint>
#include <cstddef>

#define NQ 4
#define DIM 64
#define FAN 68
#define T_TOTAL 128
#define BATCH 4096

// quad_perm DPP controls: ctrl = p0 | p1<<2 | p2<<4 | p3<<6
#define DPP_XOR1 0xB1   // [1,0,3,2]
#define DPP_XOR2 0x4E   // [2,3,0,1]

template <int CTRL>
__device__ __forceinline__ float dppq(float x) {
    return __int_as_float(
        __builtin_amdgcn_update_dpp(0, __float_as_int(x), CTRL, 0xF, 0xF, true));
}

__device__ __forceinline__ float fastrcp(float x) {
    return __builtin_amdgcn_rcpf(x);
}

// K1: pre[row,16] = x[row,0:64] @ W[:,0:64]^T + b + theta   (row = t*B + b within chunk)
__global__ __launch_bounds__(256) void qlstm_pre(
    const float* __restrict__ x,   // [nrows, 64]
    const float* __restrict__ Wf, const float* __restrict__ bf,
    const float* __restrict__ Wi, const float* __restrict__ bi,
    const float* __restrict__ Wu, const float* __restrict__ bu,
    const float* __restrict__ Wo, const float* __restrict__ bo,
    const float* __restrict__ thetas,   // [4,4]
    float* __restrict__ pre,            // [nrows, 16]
    int nrows)
{
    int row = blockIdx.x * 256 + threadIdx.x;
    if (row >= nrows) return;

    const float4* xv = reinterpret_cast<const float4*>(x + (size_t)row * DIM);
    float4 xr[16];
#pragma unroll
    for (int j = 0; j < 16; ++j) xr[j] = xv[j];

    const float* Ws[4] = {Wf, Wi, Wu, Wo};
    const float* bs[4] = {bf, bi, bu, bo};

    float acc[16];
#pragma unroll
    for (int G = 0; G < 4; ++G) {
#pragma unroll
        for (int q = 0; q < NQ; ++q) {
            float a = bs[G][q] + thetas[G * NQ + q];
            const float4* wr = reinterpret_cast<const float4*>(Ws[G] + q * FAN);
#pragma unroll
            for (int j = 0; j < 16; ++j) {
                float4 w = wr[j];
                a = fmaf(xr[j].x, w.x, a);
                a = fmaf(xr[j].y, w.y, a);
                a = fmaf(xr[j].z, w.z, a);
                a = fmaf(xr[j].w, w.w, a);
            }
            acc[G * 4 + q] = a;
        }
    }

    float4* pv = reinterpret_cast<float4*>(pre + (size_t)row * 16);
#pragma unroll
    for (int k = 0; k < 4; ++k)
        pv[k] = make_float4(acc[4 * k], acc[4 * k + 1], acc[4 * k + 2], acc[4 * k + 3]);
}

// K2: recurrence, 4 lanes per batch element (lane-gate: 0=I, 1=U, 2=F, 3=O).
// 256 blocks x 64 threads -> 16 batch elems/block, all 256 CUs active.
__global__ __launch_bounds__(64) void qlstm_rec(
    const float* __restrict__ pre,   // [chunkT, B, 16]  inner: slot(f,i,u,o)*4 + q
    const float* __restrict__ Wf, const float* __restrict__ Wi,
    const float* __restrict__ Wu, const float* __restrict__ Wo,
    float* __restrict__ out,
    float* __restrict__ state,       // [2, B, 4]  (h then c)
    int t0, int chunkT, int isFirst, int isLast)
{
    const int tid = threadIdx.x;
    const int g   = tid & 3;       // lane-gate: 0=I,1=U,2=F,3=O
    const int lb  = tid >> 2;      // 0..15
    const int b   = blockIdx.x * 16 + lb;

    // lane-gate -> W pointer and pre slot (pre slots are f,i,u,o)
    const float* W = (g == 0) ? Wi : (g == 1) ? Wu : (g == 2) ? Wf : Wo;
    const int slot = (g == 0) ? 1  : (g == 1) ? 2  : (g == 2) ? 0  : 3;

    float wh[4][4];
#pragma unroll
    for (int q = 0; q < 4; ++q)
#pragma unroll
        for (int j = 0; j < 4; ++j)
            wh[q][j] = W[q * FAN + DIM + j];

    const bool is_u  = (g == 1);
    const bool is_g2 = (g == 2);
    const bool is_g3 = (g == 3);
    const bool hi    = (g >= 2);

    const float A  = is_u ? 2.0f : 1.0f;   // act = A*sigmoid(B*z)+C ; tanh(z)=2*sig(2z)-1
    const float nB = is_u ? -2.0f : -1.0f;
    const float C  = is_u ? -1.0f : 0.0f;

    float h[4], c[4];
    if (isFirst) {
#pragma unroll
        for (int k = 0; k < 4; ++k) { h[k] = 0.0f; c[k] = 0.0f; }
    } else {
        float4 hv = *reinterpret_cast<const float4*>(state + (size_t)b * 4);
        float4 cv = *reinterpret_cast<const float4*>(state + (size_t)BATCH * 4 + (size_t)b * 4);
        h[0] = hv.x; h[1] = hv.y; h[2] = hv.z; h[3] = hv.w;
        c[0] = cv.x; c[1] = cv.y; c[2] = cv.z; c[3] = cv.w;
    }

    const char* pbase = (const char*)(pre + ((size_t)b * 16 + slot * 4));
    const size_t strideB = (size_t)BATCH * 16 * sizeof(float);

    // depth-4 register ring prefetch of this lane's 16B/step
    float4 ring[4];
#pragma unroll
    for (int d = 0; d < 4; ++d) {
        int td = (d < chunkT) ? d : (chunkT - 1);
        ring[d] = *reinterpret_cast<const float4*>(pbase + (size_t)td * strideB);
    }

    for (int tt = 0; tt < chunkT; tt += 4) {
#pragma unroll
        for (int u = 0; u < 4; ++u) {
            int t = tt + u;
            if (t >= chunkT) break;              // wave-uniform
            float4 pv = ring[u];
            int tf = (t + 4 < chunkT) ? (t + 4) : (chunkT - 1);
            ring[u] = *reinterpret_cast<const float4*>(pbase + (size_t)tf * strideB);

            // angles for this lane's gate
            float a0 = pv.x, a1 = pv.y, a2 = pv.z, a3 = pv.w;
#pragma unroll
            for (int j = 0; j < 4; ++j) {
                a0 = fmaf(wh[0][j], h[j], a0);
                a1 = fmaf(wh[1][j], h[j], a1);
                a2 = fmaf(wh[2][j], h[j], a2);
                a3 = fmaf(wh[3][j], h[j], a3);
            }

            float c0 = __cosf(a0), c1 = __cosf(a1), c2 = __cosf(a2), c3 = __cosf(a3);
            // PauliZ after CNOT ring: z0=c1c2c3, z1=c0c1, z2=c0c1c2, z3=c0c1c2c3
            float c12 = c1 * c2;
            float z[4];
            z[0] = c12 * c3;
            z[1] = c0 * c1;
            z[2] = c0 * c12;
            z[3] = z[2] * c3;

            // per-lane activation (sigmoid for I,F,O; tanh for U via 2*sig(2z)-1)
            float act[4];
#pragma unroll
            for (int k = 0; k < 4; ++k) {
                float e = __expf(nB * z[k]);
                act[k] = fmaf(A, fastrcp(1.0f + e), C);
            }

            // exchange within the 4-lane group via quad-perm DPP
            float p1e[4], prod[4];
#pragma unroll
            for (int k = 0; k < 4; ++k) p1e[k] = dppq<DPP_XOR1>(act[k]);
            // lanes {I,U}: I*U ; lanes {F,O}: F*c
#pragma unroll
            for (int k = 0; k < 4; ++k) {
                float xk = is_g3 ? p1e[k] : act[k];
                float yk = hi    ? c[k]   : p1e[k];
                prod[k] = xk * yk;
            }
#pragma unroll
            for (int k = 0; k < 4; ++k) {
                float p2e = dppq<DPP_XOR2>(prod[k]);
                c[k] = prod[k] + p2e;            // c_new = I*U + F*c  (identical on all lanes)
            }
            float th[4];
#pragma unroll
            for (int k = 0; k < 4; ++k) {
                float e = __expf(-2.0f * c[k]);
                th[k] = fmaf(2.0f, fastrcp(1.0f + e), -1.0f);
            }
#pragma unroll
            for (int k = 0; k < 4; ++k) {
                float ov  = is_g2 ? p1e[k] : act[k];   // O at lanes 2,3
                float p3e = dppq<DPP_XOR2>(ov);        // O to lanes 0,1
                float Ov  = hi ? ov : p3e;
                h[k] = Ov * th[k];
            }

            // store wire g of h: coalesced 4B/lane
            float hg = (g == 0) ? h[0] : (g == 1) ? h[1] : (g == 2) ? h[2] : h[3];
            out[((size_t)(t0 + t) * BATCH + b) * 4 + g] = hg;
        }
    }

    float hg = (g == 0) ? h[0] : (g == 1) ? h[1] : (g == 2) ? h[2] : h[3];
    float cg = (g == 0) ? c[0] : (g == 1) ? c[1] : (g == 2) ? c[2] : c[3];
    state[(size_t)b * 4 + g] = hg;
    state[(size_t)BATCH * 4 + (size_t)b * 4 + g] = cg;

    if (isLast) {
        size_t tail = (size_t)T_TOTAL * BATCH * 4;
        out[tail + (size_t)b * 4 + g] = hg;
        out[tail + (size_t)BATCH * 4 + (size_t)b * 4 + g] = cg;
    }
}

extern "C" void kernel_launch(void* const* d_in, const int* in_sizes, int n_in,
                              void* d_out, int out_size, void* d_ws, size_t ws_size,
                              hipStream_t stream)
{
    const float* x  = (const float*)d_in[0];
    const float* Wf = (const float*)d_in[1];
    const float* bf = (const float*)d_in[2];
    const float* Wi = (const float*)d_in[3];
    const float* bi = (const float*)d_in[4];
    const float* Wu = (const float*)d_in[5];
    const float* bu = (const float*)d_in[6];
    const float* Wo = (const float*)d_in[7];
    const float* bo = (const float*)d_in[8];
    const float* th = (const float*)d_in[9];
    float* out = (float*)d_out;

    const size_t stateBytes = 2 * (size_t)BATCH * 4 * sizeof(float);  // 128 KB
    const size_t perT       = (size_t)BATCH * 16 * sizeof(float);     // 256 KB per timestep
    size_t avail = (ws_size > stateBytes) ? (ws_size - stateBytes) : 0;
    int chunkT = (int)(avail / perT);
    if (chunkT > T_TOTAL) chunkT = T_TOTAL;
    if (chunkT < 1) chunkT = 1;   // requires ws_size >= ~384KB

    float* pre = (float*)d_ws;
    size_t stateOff = (ws_size - stateBytes) & ~(size_t)15;
    float* state = (float*)((char*)d_ws + stateOff);

    for (int t0 = 0; t0 < T_TOTAL; t0 += chunkT) {
        int ct = (T_TOTAL - t0 < chunkT) ? (T_TOTAL - t0) : chunkT;
        int nrows = ct * BATCH;
        qlstm_pre<<<(nrows + 255) / 256, 256, 0, stream>>>(
            x + (size_t)t0 * BATCH * DIM,
            Wf, bf, Wi, bi, Wu, bu, Wo, bo, th, pre, nrows);
        // 16 batch elems per 64-thread block (4 lanes each) -> BATCH/16 = 256 blocks
        qlstm_rec<<<BATCH / 16, 64, 0, stream>>>(
            pre, Wf, Wi, Wu, Wo, out, state,
            t0, ct, (t0 == 0) ? 1 : 0, (t0 + ct >= T_TOTAL) ? 1 : 0);
    }
}